// Round 1
// baseline (417.906 us; speedup 1.0000x reference)
//
#include <hip/hip_runtime.h>

#define DEVFN __device__ __forceinline__

typedef short bf16x8 __attribute__((ext_vector_type(8)));
typedef float f32x4 __attribute__((ext_vector_type(4)));
typedef float f32x16 __attribute__((ext_vector_type(16)));

constexpr int NN = 384;
constexpr int MROWS = NN * NN;          // 147456
constexpr float LN_EPS = 1e-5f;
constexpr float INFB = 1000000000.0f;
constexpr float LOG2E = 1.44269504088896340736f;
constexpr float SM_SCALE = 0.17677669529663687f;  // 1/sqrt(32)

DEVFN unsigned short f2bf(float f) {
  unsigned u = __builtin_bit_cast(unsigned, f);
  u += 0x7fffu + ((u >> 16) & 1u);
  return (unsigned short)(u >> 16);
}
DEVFN float bflo(unsigned u) { return __builtin_bit_cast(float, u << 16); }
DEVFN float bfhi(unsigned u) { return __builtin_bit_cast(float, u & 0xffff0000u); }
DEVFN unsigned cvtpk(float lo, float hi) {
  unsigned d;
  asm("v_cvt_pk_bf16_f32 %0, %1, %2" : "=v"(d) : "v"(lo), "v"(hi));
  return d;
}
DEVFN void swap32(unsigned &a, unsigned &b) {
  asm volatile("v_permlane32_swap_b32 %0, %1" : "+v"(a), "+v"(b));
}
// async global->LDS, 16B per lane; LDS dest = wave-uniform base + lane*16.
DEVFN void gload16(const void* g, void* l) {
  __builtin_amdgcn_global_load_lds((const __attribute__((address_space(1))) void*)g,
                                   (__attribute__((address_space(3))) void*)l, 16, 0, 0);
}

// ---------------- K0: LayerNorm + triangle bias ----------------
// one wave per (i,j) row; lane holds channels 2l, 2l+1.
__global__ __launch_bounds__(256) void k_ln(
    const float* __restrict__ x, const float* __restrict__ ln_g,
    const float* __restrict__ ln_b, const float* __restrict__ w_tri,
    unsigned* __restrict__ xn2, unsigned short* __restrict__ trib) {
  const int lane = threadIdx.x & 63;
  const int wid = blockIdx.x * 4 + (threadIdx.x >> 6);
  const int nw = gridDim.x * 4;
  const float g0 = ln_g[2*lane], g1 = ln_g[2*lane+1];
  const float b0 = ln_b[2*lane], b1 = ln_b[2*lane+1];
  float wt[8];
#pragma unroll
  for (int h = 0; h < 4; ++h) { wt[h] = w_tri[(2*lane)*4 + h]; wt[4+h] = w_tri[(2*lane+1)*4 + h]; }
  for (int row = wid; row < MROWS; row += nw) {
    const float2 v = *(const float2*)(x + (size_t)row*128 + 2*lane);
    float s = v.x + v.y, sq = v.x*v.x + v.y*v.y;
#pragma unroll
    for (int o = 1; o < 64; o <<= 1) { s += __shfl_xor(s, o, 64); sq += __shfl_xor(sq, o, 64); }
    const float mu = s * 0.0078125f;
    const float rs = rsqrtf(sq * 0.0078125f - mu*mu + LN_EPS);
    const float xn0 = (v.x - mu)*rs*g0 + b0;
    const float xn1 = (v.y - mu)*rs*g1 + b1;
    xn2[(size_t)row*64 + lane] = cvtpk(xn0, xn1);
    float t0 = xn0*wt[0] + xn1*wt[4];
    float t1 = xn0*wt[1] + xn1*wt[5];
    float t2 = xn0*wt[2] + xn1*wt[6];
    float t3 = xn0*wt[3] + xn1*wt[7];
#pragma unroll
    for (int o = 1; o < 64; o <<= 1) {
      t0 += __shfl_xor(t0, o, 64); t1 += __shfl_xor(t1, o, 64);
      t2 += __shfl_xor(t2, o, 64); t3 += __shfl_xor(t3, o, 64);
    }
    if (lane < 4) {
      const float tv = lane==0?t0 : lane==1?t1 : lane==2?t2 : t3;
      const int i = row / NN, j = row - i*NN;
      // tri_b[h][j>>5][i][j&31]  (h = lane)
      trib[(((size_t)lane*12 + (j>>5))*NN + i)*32 + (j&31)] = f2bf(tv);
    }
  }
}

// ---------------- K1: projections (Q,K,V,G) ----------------
// grid = 2304 m-tiles x 4 (nb selects Q/K/V/G). BM=64, BN=128, K=128.
__global__ __launch_bounds__(256) void k_proj(
    const unsigned short* __restrict__ xn, const unsigned short* __restrict__ Wt,
    const float* __restrict__ bg,
    unsigned short* __restrict__ Qb, unsigned short* __restrict__ Kb,
    unsigned short* __restrict__ VTb, unsigned short* __restrict__ Gb) {
  __shared__ __align__(16) char lds[49152];
  const int tid = threadIdx.x;
  const int lane = tid & 63, w = tid >> 6;
  const int nb = blockIdx.x & 3, mt = blockIdx.x >> 2;
  const int m00 = mt * 64;
  const int l15 = lane & 15, l4 = lane >> 4;
  // stage A (xn tile, fragment-contiguous)
  const char* Ag = (const char*)xn + (size_t)m00 * 256;
#pragma unroll
  for (int c = 0; c < 4; ++c) {
    const int fa = w*4 + c;  // fa = mr*4 + kk
    gload16(Ag + ((fa>>2)*16 + l15)*256 + (fa&3)*64 + l4*16, lds + fa*1024);
  }
  // stage B (Wt slice [128 n][128 k] bf16)
  const char* Bg = (const char*)Wt + (size_t)nb * 128 * 256;
#pragma unroll
  for (int c = 0; c < 8; ++c) {
    const int fb = w*8 + c;  // fb = nr*4 + kk
    gload16(Bg + ((fb>>2)*16 + l15)*256 + (fb&3)*64 + l4*16, lds + 16384 + fb*1024);
  }
  __syncthreads();
  const int wm = w >> 1, wn = w & 1;
  f32x4 acc[2][4] = {};
#pragma unroll
  for (int kk = 0; kk < 4; ++kk) {
    bf16x8 a[2], b[4];
#pragma unroll
    for (int mi = 0; mi < 2; ++mi)
      a[mi] = *(const bf16x8*)(lds + ((wm*2+mi)*4 + kk)*1024 + lane*16);
#pragma unroll
    for (int ni = 0; ni < 4; ++ni)
      b[ni] = *(const bf16x8*)(lds + 16384 + ((wn*4+ni)*4 + kk)*1024 + lane*16);
#pragma unroll
    for (int mi = 0; mi < 2; ++mi)
#pragma unroll
      for (int ni = 0; ni < 4; ++ni)
        acc[mi][ni] = __builtin_amdgcn_mfma_f32_16x16x32_bf16(a[mi], b[ni], acc[mi][ni], 0, 0, 0);
  }
  const int i0 = m00 / NN;
  const int j0 = m00 - i0*NN;
  if (nb != 2) {
    unsigned short* dst = nb==0 ? Qb : (nb==1 ? Kb : Gb);
    float bgv[4] = {0.f,0.f,0.f,0.f};
    if (nb == 3) {
#pragma unroll
      for (int ni = 0; ni < 4; ++ni) bgv[ni] = bg[wn*64 + ni*16 + l15];
    }
#pragma unroll
    for (int mi = 0; mi < 2; ++mi)
#pragma unroll
      for (int ni = 0; ni < 4; ++ni) {
        const int n = wn*64 + ni*16 + l15;
#pragma unroll
        for (int r = 0; r < 4; ++r) {
          const int j = j0 + wm*32 + mi*16 + l4*4 + r;
          float v = acc[mi][ni][r];
          if (nb == 3) v = 1.f / (1.f + exp2f(-(v + bgv[ni]) * LOG2E));
          // [i][h][j][32]
          dst[(((size_t)(i0*4 + (n>>5))*NN) + j)*32 + (n&31)] = f2bf(v);
        }
      }
  } else {
    // V: transpose tile via LDS, store VT[i][h][c][j]
    __syncthreads();
    float* T = (float*)lds;
#pragma unroll
    for (int mi = 0; mi < 2; ++mi)
#pragma unroll
      for (int ni = 0; ni < 4; ++ni) {
        const int n = wn*64 + ni*16 + l15;
#pragma unroll
        for (int r = 0; r < 4; ++r)
          T[n*65 + wm*32 + mi*16 + l4*4 + r] = acc[mi][ni][r];
      }
    __syncthreads();
#pragma unroll
    for (int it = 0; it < 4; ++it) {
      const int slot = it*256 + tid;
      const int n = slot >> 3, j8 = (slot & 7)*8;
      const float* src = T + n*65 + j8;
      uint4 pk;
      pk.x = cvtpk(src[0], src[1]); pk.y = cvtpk(src[2], src[3]);
      pk.z = cvtpk(src[4], src[5]); pk.w = cvtpk(src[6], src[7]);
      *(uint4*)((char*)VTb + ((((size_t)(i0*4 + (n>>5))*32) + (n&31))*NN + j0 + j8)*2) = pk;
    }
  }
}

// ---------------- K2: fused attention per (i, h) ----------------
// swapped QK^T (mfma(K,Q)), online softmax lane-local, O^T = mfma(VT, P^T).
__global__ __launch_bounds__(256) void k_attn(
    const unsigned short* __restrict__ Qb, const unsigned short* __restrict__ Kb,
    const unsigned short* __restrict__ VTb, const unsigned short* __restrict__ trib,
    const float* __restrict__ mask,
    const unsigned short* Gb, unsigned short* opre) {  // Gb/opre alias: no restrict
  __shared__ __align__(16) char lds[50688];
  const int tid = threadIdx.x;
  const int lane = tid & 63, w = tid >> 6;
  const int i = blockIdx.x >> 2, h = blockIdx.x & 3;
  const int lo = lane & 31, hi = lane >> 5;
  const size_t ih = (size_t)(i*4 + h);
  const char* Kg = (const char*)Kb + ih * 384 * 64;
  const char* Vg = (const char*)VTb + ih * 32 * 768;
  // K frags: fk = kt*2 + dc (A-operand of 32x32x16: row k, 16-d chunk)
#pragma unroll
  for (int c = 0; c < 6; ++c) {
    const int fk = w*6 + c;
    gload16(Kg + ((fk>>1)*32 + lo)*64 + (fk&1)*32 + hi*16, lds + fk*1024);
  }
  // VT frags: fv = 16-k chunk index
#pragma unroll
  for (int c = 0; c < 6; ++c) {
    const int fv = w*6 + c;
    gload16(Vg + lo*768 + fv*32 + hi*16, lds + 24576 + fv*1024);
  }
  float* mb = (float*)(lds + 49152);
  for (int j = tid; j < 384; j += 256) mb[j] = INFB * (mask[i*384 + j] - 1.f);
  __syncthreads();
  const char* Qg = (const char*)Qb + ih * 384 * 64;
  for (int it = 0; it < 3; ++it) {
    const int qg = (it*4 + w)*32 + lo;  // this lane's q column
    bf16x8 qf[2];
    qf[0] = *(const bf16x8*)(Qg + qg*64 + hi*16);
    qf[1] = *(const bf16x8*)(Qg + qg*64 + 32 + hi*16);
    f32x16 O;
#pragma unroll
    for (int r = 0; r < 16; ++r) O[r] = 0.f;
    float m_r = -1e30f, l_r = 0.f;
    for (int kt = 0; kt < 12; ++kt) {
      f32x16 st;
#pragma unroll
      for (int r = 0; r < 16; ++r) st[r] = 0.f;
#pragma unroll
      for (int dc = 0; dc < 2; ++dc) {
        const bf16x8 ka = *(const bf16x8*)(lds + (kt*2+dc)*1024 + lane*16);
        st = __builtin_amdgcn_mfma_f32_32x32x16_bf16(ka, qf[dc], st, 0, 0, 0);
      }
      // reg r holds S^T[k_local = 8*(r>>2) + 4*hi + (r&3)][q = qg]
      const char* trow = (const char*)trib + (((size_t)(h*12 + kt)*384 + qg)*32)*2;
      float s[16];
#pragma unroll
      for (int rr = 0; rr < 4; ++rr) {
        const uint2 tv = *(const uint2*)(trow + (8*rr + 4*hi)*2);
        const float4 mv = *(const float4*)(mb + kt*32 + 8*rr + 4*hi);
        s[rr*4+0] = st[rr*4+0]*SM_SCALE + bflo(tv.x) + mv.x;
        s[rr*4+1] = st[rr*4+1]*SM_SCALE + bfhi(tv.x) + mv.y;
        s[rr*4+2] = st[rr*4+2]*SM_SCALE + bflo(tv.y) + mv.z;
        s[rr*4+3] = st[rr*4+3]*SM_SCALE + bfhi(tv.y) + mv.w;
      }
      float pmax = s[0];
#pragma unroll
      for (int r = 1; r < 16; ++r) pmax = fmaxf(pmax, s[r]);
      pmax = fmaxf(pmax, __shfl_xor(pmax, 32, 64));
      const float mnew = fmaxf(m_r, pmax);
      const float fs = exp2f((m_r - mnew) * LOG2E);
      float p[16], psum = 0.f;
#pragma unroll
      for (int r = 0; r < 16; ++r) { p[r] = exp2f((s[r] - mnew) * LOG2E); psum += p[r]; }
      psum += __shfl_xor(psum, 32, 64);
      l_r = l_r * fs + psum;
      m_r = mnew;
#pragma unroll
      for (int r = 0; r < 16; ++r) O[r] *= fs;
      // P -> bf16 B-frags: swap(w0,w2)/(w1,w3) assembles k 0..7|8..15 per half-wave
      unsigned w0 = cvtpk(p[0], p[1]),   w1 = cvtpk(p[2], p[3]);
      unsigned w2 = cvtpk(p[4], p[5]),   w3 = cvtpk(p[6], p[7]);
      unsigned w4 = cvtpk(p[8], p[9]),   w5 = cvtpk(p[10], p[11]);
      unsigned w6 = cvtpk(p[12], p[13]), w7 = cvtpk(p[14], p[15]);
      swap32(w0, w2); swap32(w1, w3); swap32(w4, w6); swap32(w5, w7);
      union { unsigned u[4]; bf16x8 v; } pa, pb;
      pa.u[0] = w0; pa.u[1] = w1; pa.u[2] = w2; pa.u[3] = w3;
      pb.u[0] = w4; pb.u[1] = w5; pb.u[2] = w6; pb.u[3] = w7;
      const bf16x8 va = *(const bf16x8*)(lds + 24576 + (kt*2)*1024 + lane*16);
      O = __builtin_amdgcn_mfma_f32_32x32x16_bf16(va, pa.v, O, 0, 0, 0);
      const bf16x8 vb = *(const bf16x8*)(lds + 24576 + (kt*2+1)*1024 + lane*16);
      O = __builtin_amdgcn_mfma_f32_32x32x16_bf16(vb, pb.v, O, 0, 0, 0);
    }
    // epilogue: normalize, gate, store gated o (aliases G buffer region we just read)
    const float rl = 1.f / l_r;
    const char* grow = (const char*)Gb + (ih*384 + qg)*64;
    char* orow = (char*)opre + (ih*384 + qg)*64;
#pragma unroll
    for (int rr = 0; rr < 4; ++rr) {
      const uint2 gv = *(const uint2*)(grow + (8*rr + 4*hi)*2);
      uint2 ov;
      ov.x = cvtpk(O[rr*4+0]*rl*bflo(gv.x), O[rr*4+1]*rl*bfhi(gv.x));
      ov.y = cvtpk(O[rr*4+2]*rl*bflo(gv.y), O[rr*4+3]*rl*bfhi(gv.y));
      *(uint2*)(orow + (8*rr + 4*hi)*2) = ov;
    }
  }
}

// ---------------- K3: output projection ----------------
__global__ __launch_bounds__(256) void k_out(
    const unsigned short* __restrict__ opre, const unsigned short* __restrict__ woT,
    const float* __restrict__ bo, float* __restrict__ out) {
  __shared__ __align__(16) char lds[32768];
  const int tid = threadIdx.x;
  const int lane = tid & 63, w = tid >> 6;
  const int m00 = blockIdx.x * 64;
  const int l15 = lane & 15, l4 = lane >> 4;
#pragma unroll
  for (int c = 0; c < 8; ++c) {
    const int fb = w*8 + c;
    gload16((const char*)woT + ((fb>>2)*16 + l15)*256 + (fb&3)*64 + l4*16, lds + fb*1024);
  }
  __syncthreads();
  const int wm = w >> 1, wn = w & 1;
  const int i0 = m00 / NN, j0 = m00 - i0*NN;
  f32x4 acc[2][4] = {};
#pragma unroll
  for (int kk = 0; kk < 4; ++kk) {  // kk == head h ; hc = kk*32 + 8*l4 + e
    bf16x8 a[2], b[4];
#pragma unroll
    for (int mi = 0; mi < 2; ++mi) {
      const int j = j0 + wm*32 + mi*16 + l15;
      a[mi] = *(const bf16x8*)((const char*)opre + ((size_t)(i0*4 + kk)*NN + j)*64 + l4*16);
    }
#pragma unroll
    for (int ni = 0; ni < 4; ++ni)
      b[ni] = *(const bf16x8*)(lds + ((wn*4+ni)*4 + kk)*1024 + lane*16);
#pragma unroll
    for (int mi = 0; mi < 2; ++mi)
#pragma unroll
      for (int ni = 0; ni < 4; ++ni)
        acc[mi][ni] = __builtin_amdgcn_mfma_f32_16x16x32_bf16(a[mi], b[ni], acc[mi][ni], 0, 0, 0);
  }
  float bov[4];
#pragma unroll
  for (int ni = 0; ni < 4; ++ni) bov[ni] = bo[wn*64 + ni*16 + l15];
#pragma unroll
  for (int mi = 0; mi < 2; ++mi)
#pragma unroll
    for (int ni = 0; ni < 4; ++ni) {
      const int n = wn*64 + ni*16 + l15;
#pragma unroll
      for (int r = 0; r < 4; ++r) {
        const int j = j0 + wm*32 + mi*16 + l4*4 + r;
        out[((size_t)i0*NN + j)*128 + n] = acc[mi][ni][r] + bov[ni];
      }
    }
}

// ---------------- weight pack ----------------
__global__ __launch_bounds__(256) void k_pack(
    const float* __restrict__ wq, const float* __restrict__ wk,
    const float* __restrict__ wv, const float* __restrict__ wg,
    const float* __restrict__ wo,
    unsigned short* __restrict__ Wt, unsigned short* __restrict__ woT) {
  const int stride = gridDim.x * 256;
  for (int o = blockIdx.x*256 + threadIdx.x; o < 81920; o += stride) {
    if (o < 65536) {
      const int row = o >> 7, k = o & 127;       // Wt[n + 128*s][k]
      const int s = row >> 7, n = row & 127;
      const float* W = s==0 ? wq : s==1 ? wk : s==2 ? wv : wg;
      Wt[o] = f2bf(W[k*128 + n]);
    } else {
      const int o2 = o - 65536;                  // woT[out][hc]
      const int n = o2 >> 7, k = o2 & 127;
      woT[o2] = f2bf(wo[k*128 + n]);
    }
  }
}

extern "C" void kernel_launch(void* const* d_in, const int* in_sizes, int n_in,
                              void* d_out, int out_size, void* d_ws, size_t ws_size,
                              hipStream_t stream) {
  const float* x     = (const float*)d_in[0];
  const float* mask  = (const float*)d_in[1];
  const float* ln_g  = (const float*)d_in[2];
  const float* ln_b  = (const float*)d_in[3];
  const float* w_tri = (const float*)d_in[4];
  const float* wq    = (const float*)d_in[5];
  const float* wk    = (const float*)d_in[6];
  const float* wv    = (const float*)d_in[7];
  const float* wg    = (const float*)d_in[8];
  const float* bg    = (const float*)d_in[9];
  const float* wo    = (const float*)d_in[10];
  const float* bo    = (const float*)d_in[11];
  float* outp = (float*)d_out;
  (void)in_sizes; (void)n_in; (void)out_size; (void)ws_size;

  char* ws = (char*)d_ws;
  size_t off = 0;
  auto carve = [&](size_t b) { char* p = ws + off; off += (b + 255) & ~(size_t)255; return p; };
  const size_t big = (size_t)MROWS * 256;  // 37.75 MB (bf16 [147456][128])
  unsigned short* xn   = (unsigned short*)carve(big);
  unsigned short* Qb   = (unsigned short*)carve(big);
  unsigned short* Kb   = (unsigned short*)carve(big);
  unsigned short* VTb  = (unsigned short*)carve(big);
  unsigned short* Gb   = (unsigned short*)carve(big);   // also holds gated o (opre)
  unsigned short* trib = (unsigned short*)carve((size_t)4*12*384*32*2);
  unsigned short* Wt   = (unsigned short*)carve(512*128*2);
  unsigned short* woT  = (unsigned short*)carve(128*128*2);

  k_pack<<<96, 256, 0, stream>>>(wq, wk, wv, wg, wo, Wt, woT);
  k_ln<<<1024, 256, 0, stream>>>(x, ln_g, ln_b, w_tri, (unsigned*)xn, trib);
  k_proj<<<9216, 256, 0, stream>>>(xn, Wt, bg, Qb, Kb, VTb, Gb);
  k_attn<<<1536, 256, 0, stream>>>(Qb, Kb, VTb, trib, mask, Gb, Gb);
  k_out<<<2304, 256, 0, stream>>>(Gb, woT, bo, outp);
}